// Round 2
// baseline (481.606 us; speedup 1.0000x reference)
//
#include <hip/hip_runtime.h>
#include <hip/hip_bf16.h>

typedef unsigned short u16;
typedef unsigned int u32;

#define N_NODES 50000
#define N_EDGES 800000
#define DHID 256
#define NCHUNK 49  // ceil(50000/1024)

typedef __attribute__((ext_vector_type(8))) short bf16x8;
typedef __attribute__((ext_vector_type(4))) float f32x4;

// ---------- helpers ----------
__device__ __forceinline__ u16 f2bf(float f) {
    u32 u = __float_as_uint(f);
    u32 r = (u + 0x7FFFu + ((u >> 16) & 1u)) >> 16;
    return (u16)r;
}
__device__ __forceinline__ float bf2f(u32 bits16) {
    return __uint_as_float(bits16 << 16);
}
__device__ __forceinline__ void gl_lds16(const void* g, void* l) {
    __builtin_amdgcn_global_load_lds(
        (const __attribute__((address_space(1))) u32*)g,
        (__attribute__((address_space(3))) u32*)l, 16, 0, 0);
}

// ---------- graph prep ----------
__global__ void zero_kernel(int* __restrict__ p, int n) {
    int i = blockIdx.x * 256 + threadIdx.x;
    if (i < n) p[i] = 0;
}

__global__ void deg_kernel(const int* __restrict__ dst, int* __restrict__ deg, int E) {
    int e = blockIdx.x * 256 + threadIdx.x;
    if (e < E) atomicAdd(&deg[dst[e]], 1);
}

__global__ void invsqrt_kernel(const int* __restrict__ deg, float* __restrict__ inv, int n) {
    int i = blockIdx.x * 256 + threadIdx.x;
    if (i < n) inv[i] = 1.0f / sqrtf((float)deg[i] + 1.0f);
}

// chunked scan, step 1: inclusive scan within each 1024-chunk + chunk totals
__global__ __launch_bounds__(1024) void scan1_kernel(const int* __restrict__ deg,
                                                     int* __restrict__ partial,
                                                     int* __restrict__ totals, int n) {
    __shared__ int wsum[16];
    __shared__ int woff[16];
    const int tid = threadIdx.x, lane = tid & 63, wid = tid >> 6;
    const int idx = blockIdx.x * 1024 + tid;
    int v = (idx < n) ? deg[idx] : 0;
    int x = v;
#pragma unroll
    for (int off = 1; off < 64; off <<= 1) {
        int t = __shfl_up(x, off, 64);
        if (lane >= off) x += t;
    }
    if (lane == 63) wsum[wid] = x;
    __syncthreads();
    if (tid == 0) {
        int s = 0;
#pragma unroll
        for (int w = 0; w < 16; ++w) { woff[w] = s; s += wsum[w]; }
    }
    __syncthreads();
    x += woff[wid];
    partial[idx] = x;
    if (tid == 1023) totals[blockIdx.x] = x;
}

// step 2: exclusive scan of the 49 chunk totals
__global__ void scan2_kernel(const int* __restrict__ totals, int* __restrict__ chunkoff, int nc) {
    if (threadIdx.x == 0) {
        int s = 0;
        for (int c = 0; c < nc; ++c) { chunkoff[c] = s; s += totals[c]; }
    }
}

// step 3: exclusive row_ptr = chunkoff + inclusive - deg; cursor copy
__global__ void scan3_kernel(const int* __restrict__ deg, const int* __restrict__ partial,
                             const int* __restrict__ chunkoff, int* __restrict__ rptr,
                             int* __restrict__ cursor, int n) {
    int i = blockIdx.x * 256 + threadIdx.x;
    if (i < n) {
        int e = chunkoff[i >> 10] + partial[i] - deg[i];
        rptr[i] = e;
        cursor[i] = e;
    }
    if (i == 0) rptr[n] = N_EDGES;
}

__global__ void fill_kernel(const int* __restrict__ src, const int* __restrict__ dst,
                            int* __restrict__ cursor, int* __restrict__ col, int E) {
    int e = blockIdx.x * 256 + threadIdx.x;
    if (e < E) {
        int p = atomicAdd(&cursor[dst[e]], 1);
        col[p] = src[e];
    }
}

// ---------- fp32 -> bf16 hi/lo split (2 elems/thread) ----------
__global__ void split_kernel(const float* __restrict__ x, u16* __restrict__ hi,
                             u16* __restrict__ lo, int n2) {
    int i = blockIdx.x * 256 + threadIdx.x;
    if (i < n2) {
        float2 v = ((const float2*)x)[i];
        u16 h0 = f2bf(v.x), h1 = f2bf(v.y);
        u16 l0 = f2bf(v.x - bf2f(h0)), l1 = f2bf(v.y - bf2f(h1));
        ((u32*)hi)[i] = (u32)h0 | ((u32)h1 << 16);
        ((u32*)lo)[i] = (u32)l0 | ((u32)l1 << 16);
    }
}

// ---------- W -> W^T hi/lo split. grid (256, 2), block 256 ----------
__global__ void prepw_kernel(const float* __restrict__ W1, const float* __restrict__ W2,
                             u16* __restrict__ h1, u16* __restrict__ l1,
                             u16* __restrict__ h2, u16* __restrict__ l2) {
    int n = blockIdx.x, k = threadIdx.x;
    const float* W = blockIdx.y ? W2 : W1;
    u16* oh = blockIdx.y ? h2 : h1;
    u16* ol = blockIdx.y ? l2 : l1;
    float v = W[k * 256 + n];
    u16 hh = f2bf(v);
    oh[n * 256 + k] = hh;
    ol[n * 256 + k] = f2bf(v - bf2f(hh));
}

// ---------- GEMM: hs = (A @ W) * inv_sqrt[row], bf16 out ----------
// A as hi/lo bf16 [Nn][256] row-major (tail rows clamped); W^T hi/lo bf16 [256][256].
// 3-product split over folded K=768: kb 0..7 hi*hi, 8..15 hi*lo, 16..23 lo*hi.
__global__ __launch_bounds__(256) void gemm_split_kernel(
    const u16* __restrict__ Ahi, const u16* __restrict__ Alo,
    const u16* __restrict__ Bthi, const u16* __restrict__ Btlo,
    const float* __restrict__ inv_sqrt, u16* __restrict__ out, int M) {
    __shared__ u16 As[128 * 32];
    __shared__ u16 Bs[128 * 32];
    const int tid = threadIdx.x;
    const int wave = tid >> 6;
    const int lane = tid & 63;
    const int wm = wave >> 1, wn = wave & 1;
    const int quad = lane >> 4, l16 = lane & 15;
    const int m0 = blockIdx.x * 128;
    const int n0 = blockIdx.y * 128;

    f32x4 acc[4][4] = {};

    for (int kb = 0; kb < 24; ++kb) {
        const u16* Asrc = (kb < 16) ? Ahi : Alo;
        const u16* Bsrc = (kb >= 8 && kb < 16) ? Btlo : Bthi;
        const int koff = (kb & 7) * 32;
        __syncthreads();
#pragma unroll
        for (int r = 0; r < 2; ++r) {
            int idx = r * 256 + tid;
            int row = idx >> 2;
            int kk = (idx & 3) * 8;
            int ar = m0 + row;
            if (ar >= M) ar = M - 1;  // clamp: exact-fit A buffers, padded tail
            const u16* ga = Asrc + (size_t)ar * 256 + koff + kk;
            gl_lds16(ga, &As[(size_t)(r * 256 + wave * 64) * 8]);
            const u16* gb = Bsrc + (size_t)(n0 + row) * 256 + koff + kk;
            gl_lds16(gb, &Bs[(size_t)(r * 256 + wave * 64) * 8]);
        }
        asm volatile("s_waitcnt vmcnt(0)" ::: "memory");
        __syncthreads();

        bf16x8 af[4], bfr[4];
#pragma unroll
        for (int mi = 0; mi < 4; ++mi)
            af[mi] = *(const bf16x8*)&As[(wm * 64 + mi * 16 + l16) * 32 + quad * 8];
#pragma unroll
        for (int ni = 0; ni < 4; ++ni)
            bfr[ni] = *(const bf16x8*)&Bs[(wn * 64 + ni * 16 + l16) * 32 + quad * 8];
#pragma unroll
        for (int mi = 0; mi < 4; ++mi)
#pragma unroll
            for (int ni = 0; ni < 4; ++ni)
                acc[mi][ni] = __builtin_amdgcn_mfma_f32_16x16x32_bf16(af[mi], bfr[ni], acc[mi][ni], 0, 0, 0);
    }

#pragma unroll
    for (int mi = 0; mi < 4; ++mi) {
#pragma unroll
        for (int r = 0; r < 4; ++r) {
            int row = m0 + wm * 64 + mi * 16 + quad * 4 + r;
            if (row < M) {
                float s = inv_sqrt[row];
#pragma unroll
                for (int ni = 0; ni < 4; ++ni) {
                    int c = n0 + wn * 64 + ni * 16 + l16;
                    out[(size_t)row * 256 + c] = f2bf(acc[mi][ni][r] * s);
                }
            }
        }
    }
}

// ---------- aggregation: out[i] = relu(inv[i]*(sum_e hs[src_e] + hs[i]) + b) ----------
// one wave per node; lane covers 4 consecutive columns (8B bf16 loads).
// mode 0: write bf16 hi/lo split (feeds next GEMM). mode 1: write fp32 to d_out.
__global__ __launch_bounds__(256) void agg_kernel(
    const u16* __restrict__ hs, const int* __restrict__ rptr, const int* __restrict__ cidx,
    const float* __restrict__ inv_sqrt, const float* __restrict__ bias,
    u16* __restrict__ out_hi, u16* __restrict__ out_lo, float* __restrict__ out_f,
    int mode, int Nn) {
    const int wave = threadIdx.x >> 6, lane = threadIdx.x & 63;
    const int i = blockIdx.x * 4 + wave;
    if (i >= Nn) return;

    float a0, a1, a2, a3;
    {
        uint2 v = *(const uint2*)(hs + (size_t)i * 256 + lane * 4);
        a0 = bf2f(v.x & 0xffffu);
        a1 = bf2f(v.x >> 16);
        a2 = bf2f(v.y & 0xffffu);
        a3 = bf2f(v.y >> 16);
    }
    const int beg = rptr[i], end = rptr[i + 1];
    for (int j = beg; j < end; ++j) {
        int s = cidx[j];
        uint2 v = *(const uint2*)(hs + (size_t)s * 256 + lane * 4);
        a0 += bf2f(v.x & 0xffffu);
        a1 += bf2f(v.x >> 16);
        a2 += bf2f(v.y & 0xffffu);
        a3 += bf2f(v.y >> 16);
    }
    const float inv = inv_sqrt[i];
    float4 b = *(const float4*)(bias + lane * 4);
    float r0 = fmaxf(fmaf(a0, inv, b.x), 0.0f);
    float r1 = fmaxf(fmaf(a1, inv, b.y), 0.0f);
    float r2 = fmaxf(fmaf(a2, inv, b.z), 0.0f);
    float r3 = fmaxf(fmaf(a3, inv, b.w), 0.0f);
    const size_t o = (size_t)i * 256 + lane * 4;
    if (mode == 0) {
        u16 h0 = f2bf(r0), h1 = f2bf(r1), h2 = f2bf(r2), h3 = f2bf(r3);
        u16 l0 = f2bf(r0 - bf2f(h0)), l1 = f2bf(r1 - bf2f(h1));
        u16 l2 = f2bf(r2 - bf2f(h2)), l3 = f2bf(r3 - bf2f(h3));
        uint2 hv, lv;
        hv.x = (u32)h0 | ((u32)h1 << 16);
        hv.y = (u32)h2 | ((u32)h3 << 16);
        lv.x = (u32)l0 | ((u32)l1 << 16);
        lv.y = (u32)l2 | ((u32)l3 << 16);
        *(uint2*)(out_hi + o) = hv;
        *(uint2*)(out_lo + o) = lv;
    } else {
        *(float4*)(out_f + o) = make_float4(r0, r1, r2, r3);
    }
}

extern "C" void kernel_launch(void* const* d_in, const int* in_sizes, int n_in,
                              void* d_out, int out_size, void* d_ws, size_t ws_size,
                              hipStream_t stream) {
    const float* x = (const float*)d_in[0];
    const int* ei = (const int*)d_in[1];  // int32 per harness spec (JAX x64 off)
    const float* W1 = (const float*)d_in[2];
    const float* b1 = (const float*)d_in[3];
    const float* W2 = (const float*)d_in[4];
    const float* b2 = (const float*)d_in[5];
    float* out = (float*)d_out;

    const int Nn = N_NODES, E = N_EDGES;
    const int* srcp = ei;
    const int* dstp = ei + E;

    // d_out doubles as scratch: exactly fits hi+lo bf16 node-feature buffers.
    u16* Ahi = (u16*)d_out;
    u16* Alo = Ahi + (size_t)Nn * DHID;

    // workspace carve (~30 MB total)
    char* p = (char*)d_ws;
    auto take = [&](size_t bytes) -> void* {
        void* r = (void*)p;
        p += (bytes + 255) & ~(size_t)255;
        return r;
    };
    u16* hs      = (u16*)take((size_t)Nn * DHID * 2);       // 25.6 MB
    int* col     = (int*)take((size_t)E * 4);                // 3.2 MB
    int* deg     = (int*)take((size_t)Nn * 4);
    int* cursor  = (int*)take((size_t)Nn * 4);
    int* rptr    = (int*)take((size_t)(Nn + 1) * 4);
    float* inv   = (float*)take((size_t)Nn * 4);
    int* partial = (int*)take((size_t)NCHUNK * 1024 * 4);
    int* totals  = (int*)take(64 * 4);
    int* chunkoff= (int*)take(64 * 4);
    u16* W1t_hi  = (u16*)take(256 * 256 * 2);
    u16* W1t_lo  = (u16*)take(256 * 256 * 2);
    u16* W2t_hi  = (u16*)take(256 * 256 * 2);
    u16* W2t_lo  = (u16*)take(256 * 256 * 2);

    const int nb = (Nn + 255) / 256;
    zero_kernel<<<nb, 256, 0, stream>>>(deg, Nn);
    deg_kernel<<<E / 256, 256, 0, stream>>>(dstp, deg, E);
    invsqrt_kernel<<<nb, 256, 0, stream>>>(deg, inv, Nn);
    scan1_kernel<<<NCHUNK, 1024, 0, stream>>>(deg, partial, totals, Nn);
    scan2_kernel<<<1, 64, 0, stream>>>(totals, chunkoff, NCHUNK);
    scan3_kernel<<<nb, 256, 0, stream>>>(deg, partial, chunkoff, rptr, cursor, Nn);
    fill_kernel<<<E / 256, 256, 0, stream>>>(srcp, dstp, cursor, col, E);

    split_kernel<<<(Nn * DHID / 2 + 255) / 256, 256, 0, stream>>>(x, Ahi, Alo, Nn * DHID / 2);
    prepw_kernel<<<dim3(256, 2), 256, 0, stream>>>(W1, W2, W1t_hi, W1t_lo, W2t_hi, W2t_lo);

    const int gm = (Nn + 127) / 128;  // 391
    // layer 1
    gemm_split_kernel<<<dim3(gm, 2), 256, 0, stream>>>(Ahi, Alo, W1t_hi, W1t_lo, inv, hs, Nn);
    agg_kernel<<<(Nn + 3) / 4, 256, 0, stream>>>(hs, rptr, col, inv, b1, Ahi, Alo, nullptr, 0, Nn);
    // layer 2
    gemm_split_kernel<<<dim3(gm, 2), 256, 0, stream>>>(Ahi, Alo, W2t_hi, W2t_lo, inv, hs, Nn);
    agg_kernel<<<(Nn + 3) / 4, 256, 0, stream>>>(hs, rptr, col, inv, b2, nullptr, nullptr, out, 1, Nn);
}

// Round 3
// 394.376 us; speedup vs baseline: 1.2212x; 1.2212x over previous
//
#include <hip/hip_runtime.h>
#include <hip/hip_bf16.h>

typedef unsigned short u16;
typedef unsigned int u32;

#define N_NODES 50000
#define N_EDGES 800000
#define DHID 256
#define NCHUNK 49  // ceil(50000/1024)

typedef __attribute__((ext_vector_type(8))) short bf16x8;
typedef __attribute__((ext_vector_type(4))) float f32x4;

// ---------- helpers ----------
__device__ __forceinline__ u16 f2bf(float f) {
    u32 u = __float_as_uint(f);
    u32 r = (u + 0x7FFFu + ((u >> 16) & 1u)) >> 16;
    return (u16)r;
}
__device__ __forceinline__ float bf2f(u32 bits16) {
    return __uint_as_float(bits16 << 16);
}
__device__ __forceinline__ void gl_lds16(const void* g, void* l) {
    __builtin_amdgcn_global_load_lds(
        (const __attribute__((address_space(1))) u32*)g,
        (__attribute__((address_space(3))) u32*)l, 16, 0, 0);
}

// ---------- graph prep ----------
__global__ void zero_kernel(int* __restrict__ p, int n) {
    int i = blockIdx.x * 256 + threadIdx.x;
    if (i < n) p[i] = 0;
}

__global__ void deg_kernel(const int* __restrict__ dst, int* __restrict__ deg, int E) {
    int e = blockIdx.x * 256 + threadIdx.x;
    if (e < E) atomicAdd(&deg[dst[e]], 1);
}

__global__ void invsqrt_kernel(const int* __restrict__ deg, float* __restrict__ inv, int n) {
    int i = blockIdx.x * 256 + threadIdx.x;
    if (i < n) inv[i] = 1.0f / sqrtf((float)deg[i] + 1.0f);
}

// chunked scan, step 1: inclusive scan within each 1024-chunk + chunk totals
__global__ __launch_bounds__(1024) void scan1_kernel(const int* __restrict__ deg,
                                                     int* __restrict__ partial,
                                                     int* __restrict__ totals, int n) {
    __shared__ int wsum[16];
    __shared__ int woff[16];
    const int tid = threadIdx.x, lane = tid & 63, wid = tid >> 6;
    const int idx = blockIdx.x * 1024 + tid;
    int v = (idx < n) ? deg[idx] : 0;
    int x = v;
#pragma unroll
    for (int off = 1; off < 64; off <<= 1) {
        int t = __shfl_up(x, off, 64);
        if (lane >= off) x += t;
    }
    if (lane == 63) wsum[wid] = x;
    __syncthreads();
    if (tid == 0) {
        int s = 0;
#pragma unroll
        for (int w = 0; w < 16; ++w) { woff[w] = s; s += wsum[w]; }
    }
    __syncthreads();
    x += woff[wid];
    partial[idx] = x;
    if (tid == 1023) totals[blockIdx.x] = x;
}

// step 2: exclusive scan of the 49 chunk totals — one wave, shuffle scan
__global__ void scan2_kernel(const int* __restrict__ totals, int* __restrict__ chunkoff, int nc) {
    const int lane = threadIdx.x & 63;
    int v = (lane < nc) ? totals[lane] : 0;
    int x = v;
#pragma unroll
    for (int off = 1; off < 64; off <<= 1) {
        int t = __shfl_up(x, off, 64);
        if (lane >= off) x += t;
    }
    if (lane < nc) chunkoff[lane] = x - v;
}

// step 3: exclusive row_ptr = chunkoff + inclusive - deg; cursor copy
__global__ void scan3_kernel(const int* __restrict__ deg, const int* __restrict__ partial,
                             const int* __restrict__ chunkoff, int* __restrict__ rptr,
                             int* __restrict__ cursor, int n) {
    int i = blockIdx.x * 256 + threadIdx.x;
    if (i < n) {
        int e = chunkoff[i >> 10] + partial[i] - deg[i];
        rptr[i] = e;
        cursor[i] = e;
    }
    if (i == 0) rptr[n] = N_EDGES;
}

__global__ void fill_kernel(const int* __restrict__ src, const int* __restrict__ dst,
                            int* __restrict__ cursor, int* __restrict__ col, int E) {
    int e = blockIdx.x * 256 + threadIdx.x;
    if (e < E) {
        int p = atomicAdd(&cursor[dst[e]], 1);
        col[p] = src[e];
    }
}

// ---------- fp32 -> bf16 hi/lo split (2 elems/thread) ----------
__global__ void split_kernel(const float* __restrict__ x, u16* __restrict__ hi,
                             u16* __restrict__ lo, int n2) {
    int i = blockIdx.x * 256 + threadIdx.x;
    if (i < n2) {
        float2 v = ((const float2*)x)[i];
        u16 h0 = f2bf(v.x), h1 = f2bf(v.y);
        u16 l0 = f2bf(v.x - bf2f(h0)), l1 = f2bf(v.y - bf2f(h1));
        ((u32*)hi)[i] = (u32)h0 | ((u32)h1 << 16);
        ((u32*)lo)[i] = (u32)l0 | ((u32)l1 << 16);
    }
}

// ---------- W -> W^T hi/lo split. grid (256, 2), block 256 ----------
__global__ void prepw_kernel(const float* __restrict__ W1, const float* __restrict__ W2,
                             u16* __restrict__ h1, u16* __restrict__ l1,
                             u16* __restrict__ h2, u16* __restrict__ l2) {
    int n = blockIdx.x, k = threadIdx.x;
    const float* W = blockIdx.y ? W2 : W1;
    u16* oh = blockIdx.y ? h2 : h1;
    u16* ol = blockIdx.y ? l2 : l1;
    float v = W[k * 256 + n];
    u16 hh = f2bf(v);
    oh[n * 256 + k] = hh;
    ol[n * 256 + k] = f2bf(v - bf2f(hh));
}

// ---------- GEMM: hs = (A @ W) * inv_sqrt[row], bf16 out ----------
// A as hi/lo bf16 [Nn][256] row-major (tail rows clamped); W^T hi/lo bf16 [256][256].
// 8 K-chunks of 32; per chunk stage Ah/Al/Bh/Bl and fire all 3 split products
// (hi*hi + hi*lo + lo*hi) — each tile fetched exactly once, 8 barriers not 24.
__global__ __launch_bounds__(256) void gemm_split_kernel(
    const u16* __restrict__ Ahi, const u16* __restrict__ Alo,
    const u16* __restrict__ Bthi, const u16* __restrict__ Btlo,
    const float* __restrict__ inv_sqrt, u16* __restrict__ out, int M) {
    __shared__ u16 Ah[128 * 32];
    __shared__ u16 Al[128 * 32];
    __shared__ u16 Bh[128 * 32];
    __shared__ u16 Bl[128 * 32];
    const int tid = threadIdx.x;
    const int wave = tid >> 6;
    const int lane = tid & 63;
    const int wm = wave >> 1, wn = wave & 1;
    const int quad = lane >> 4, l16 = lane & 15;
    const int m0 = blockIdx.x * 128;
    const int n0 = blockIdx.y * 128;

    f32x4 acc[4][4] = {};

    // loop-invariant staging coordinates
    const int row0 = tid >> 2, row1 = (256 + tid) >> 2;
    const int kk = (tid & 3) * 8;
    int ar0 = m0 + row0; if (ar0 >= M) ar0 = M - 1;
    int ar1 = m0 + row1; if (ar1 >= M) ar1 = M - 1;
    const size_t aoff0 = (size_t)ar0 * 256 + kk;
    const size_t aoff1 = (size_t)ar1 * 256 + kk;
    const size_t boff0 = (size_t)(n0 + row0) * 256 + kk;
    const size_t boff1 = (size_t)(n0 + row1) * 256 + kk;
    const size_t l0 = (size_t)(wave * 64) * 8;
    const size_t l1 = (size_t)(256 + wave * 64) * 8;

    for (int ko = 0; ko < 8; ++ko) {
        const int koff = ko * 32;
        __syncthreads();
        gl_lds16(Ahi + aoff0 + koff, &Ah[l0]);
        gl_lds16(Ahi + aoff1 + koff, &Ah[l1]);
        gl_lds16(Alo + aoff0 + koff, &Al[l0]);
        gl_lds16(Alo + aoff1 + koff, &Al[l1]);
        gl_lds16(Bthi + boff0 + koff, &Bh[l0]);
        gl_lds16(Bthi + boff1 + koff, &Bh[l1]);
        gl_lds16(Btlo + boff0 + koff, &Bl[l0]);
        gl_lds16(Btlo + boff1 + koff, &Bl[l1]);
        asm volatile("s_waitcnt vmcnt(0)" ::: "memory");
        __syncthreads();

        bf16x8 ah[4], al[4], bh[4], bl[4];
#pragma unroll
        for (int mi = 0; mi < 4; ++mi) {
            const int r = (wm * 64 + mi * 16 + l16) * 32 + quad * 8;
            ah[mi] = *(const bf16x8*)&Ah[r];
            al[mi] = *(const bf16x8*)&Al[r];
        }
#pragma unroll
        for (int ni = 0; ni < 4; ++ni) {
            const int r = (wn * 64 + ni * 16 + l16) * 32 + quad * 8;
            bh[ni] = *(const bf16x8*)&Bh[r];
            bl[ni] = *(const bf16x8*)&Bl[r];
        }
#pragma unroll
        for (int mi = 0; mi < 4; ++mi)
#pragma unroll
            for (int ni = 0; ni < 4; ++ni) {
                acc[mi][ni] = __builtin_amdgcn_mfma_f32_16x16x32_bf16(ah[mi], bh[ni], acc[mi][ni], 0, 0, 0);
                acc[mi][ni] = __builtin_amdgcn_mfma_f32_16x16x32_bf16(ah[mi], bl[ni], acc[mi][ni], 0, 0, 0);
                acc[mi][ni] = __builtin_amdgcn_mfma_f32_16x16x32_bf16(al[mi], bh[ni], acc[mi][ni], 0, 0, 0);
            }
    }

#pragma unroll
    for (int mi = 0; mi < 4; ++mi) {
#pragma unroll
        for (int r = 0; r < 4; ++r) {
            int row = m0 + wm * 64 + mi * 16 + quad * 4 + r;
            if (row < M) {
                float s = inv_sqrt[row];
#pragma unroll
                for (int ni = 0; ni < 4; ++ni) {
                    int c = n0 + wn * 64 + ni * 16 + l16;
                    out[(size_t)row * 256 + c] = f2bf(acc[mi][ni][r] * s);
                }
            }
        }
    }
}

// ---------- aggregation: out[i] = relu(inv[i]*(sum_e hs[src_e] + hs[i]) + b) ----------
// one wave per node. Up to 64 neighbor indices preloaded with ONE coalesced load,
// broadcast via readlane (scalar gather base), unrolled x4 for 4 gathers in flight.
__global__ __launch_bounds__(256) void agg_kernel(
    const u16* __restrict__ hs, const int* __restrict__ rptr, const int* __restrict__ cidx,
    const float* __restrict__ inv_sqrt, const float* __restrict__ bias,
    u16* __restrict__ out_hi, u16* __restrict__ out_lo, float* __restrict__ out_f,
    int mode, int Nn) {
    const int wave = threadIdx.x >> 6, lane = threadIdx.x & 63;
    const int i = blockIdx.x * 4 + wave;
    if (i >= Nn) return;

    const int beg = rptr[i], end = rptr[i + 1];
    const int cnt = end - beg;
    const int myidx = (lane < cnt) ? cidx[beg + lane] : 0;  // one coalesced index load

    float a0, a1, a2, a3;
    {
        uint2 v = *(const uint2*)(hs + (size_t)i * 256 + lane * 4);
        a0 = bf2f(v.x & 0xffffu);
        a1 = bf2f(v.x >> 16);
        a2 = bf2f(v.y & 0xffffu);
        a3 = bf2f(v.y >> 16);
    }

    const int cnt64 = cnt < 64 ? cnt : 64;
    int j = 0;
    for (; j + 4 <= cnt64; j += 4) {
        const int s0 = __builtin_amdgcn_readlane(myidx, j + 0);
        const int s1 = __builtin_amdgcn_readlane(myidx, j + 1);
        const int s2 = __builtin_amdgcn_readlane(myidx, j + 2);
        const int s3 = __builtin_amdgcn_readlane(myidx, j + 3);
        uint2 v0 = *(const uint2*)(hs + (size_t)s0 * 256 + lane * 4);
        uint2 v1 = *(const uint2*)(hs + (size_t)s1 * 256 + lane * 4);
        uint2 v2 = *(const uint2*)(hs + (size_t)s2 * 256 + lane * 4);
        uint2 v3 = *(const uint2*)(hs + (size_t)s3 * 256 + lane * 4);
        a0 += bf2f(v0.x & 0xffffu) + bf2f(v1.x & 0xffffu) + bf2f(v2.x & 0xffffu) + bf2f(v3.x & 0xffffu);
        a1 += bf2f(v0.x >> 16)     + bf2f(v1.x >> 16)     + bf2f(v2.x >> 16)     + bf2f(v3.x >> 16);
        a2 += bf2f(v0.y & 0xffffu) + bf2f(v1.y & 0xffffu) + bf2f(v2.y & 0xffffu) + bf2f(v3.y & 0xffffu);
        a3 += bf2f(v0.y >> 16)     + bf2f(v1.y >> 16)     + bf2f(v2.y >> 16)     + bf2f(v3.y >> 16);
    }
    for (; j < cnt64; ++j) {
        const int s = __builtin_amdgcn_readlane(myidx, j);
        uint2 v = *(const uint2*)(hs + (size_t)s * 256 + lane * 4);
        a0 += bf2f(v.x & 0xffffu);
        a1 += bf2f(v.x >> 16);
        a2 += bf2f(v.y & 0xffffu);
        a3 += bf2f(v.y >> 16);
    }
    for (int jj = beg + 64; jj < end; ++jj) {  // rare: deg > 64
        const int s = cidx[jj];
        uint2 v = *(const uint2*)(hs + (size_t)s * 256 + lane * 4);
        a0 += bf2f(v.x & 0xffffu);
        a1 += bf2f(v.x >> 16);
        a2 += bf2f(v.y & 0xffffu);
        a3 += bf2f(v.y >> 16);
    }

    const float inv = inv_sqrt[i];
    float4 b = *(const float4*)(bias + lane * 4);
    float r0 = fmaxf(fmaf(a0, inv, b.x), 0.0f);
    float r1 = fmaxf(fmaf(a1, inv, b.y), 0.0f);
    float r2 = fmaxf(fmaf(a2, inv, b.z), 0.0f);
    float r3 = fmaxf(fmaf(a3, inv, b.w), 0.0f);
    const size_t o = (size_t)i * 256 + lane * 4;
    if (mode == 0) {
        u16 h0 = f2bf(r0), h1 = f2bf(r1), h2 = f2bf(r2), h3 = f2bf(r3);
        u16 l0 = f2bf(r0 - bf2f(h0)), l1 = f2bf(r1 - bf2f(h1));
        u16 l2 = f2bf(r2 - bf2f(h2)), l3 = f2bf(r3 - bf2f(h3));
        uint2 hv, lv;
        hv.x = (u32)h0 | ((u32)h1 << 16);
        hv.y = (u32)h2 | ((u32)h3 << 16);
        lv.x = (u32)l0 | ((u32)l1 << 16);
        lv.y = (u32)l2 | ((u32)l3 << 16);
        *(uint2*)(out_hi + o) = hv;
        *(uint2*)(out_lo + o) = lv;
    } else {
        *(float4*)(out_f + o) = make_float4(r0, r1, r2, r3);
    }
}

extern "C" void kernel_launch(void* const* d_in, const int* in_sizes, int n_in,
                              void* d_out, int out_size, void* d_ws, size_t ws_size,
                              hipStream_t stream) {
    const float* x = (const float*)d_in[0];
    const int* ei = (const int*)d_in[1];  // int32 per harness spec (JAX x64 off)
    const float* W1 = (const float*)d_in[2];
    const float* b1 = (const float*)d_in[3];
    const float* W2 = (const float*)d_in[4];
    const float* b2 = (const float*)d_in[5];
    float* out = (float*)d_out;

    const int Nn = N_NODES, E = N_EDGES;
    const int* srcp = ei;
    const int* dstp = ei + E;

    // d_out doubles as scratch: exactly fits hi+lo bf16 node-feature buffers.
    u16* Ahi = (u16*)d_out;
    u16* Alo = Ahi + (size_t)Nn * DHID;

    // workspace carve (~30 MB total)
    char* p = (char*)d_ws;
    auto take = [&](size_t bytes) -> void* {
        void* r = (void*)p;
        p += (bytes + 255) & ~(size_t)255;
        return r;
    };
    u16* hs      = (u16*)take((size_t)Nn * DHID * 2);       // 25.6 MB
    int* col     = (int*)take((size_t)E * 4);                // 3.2 MB
    int* deg     = (int*)take((size_t)Nn * 4);
    int* cursor  = (int*)take((size_t)Nn * 4);
    int* rptr    = (int*)take((size_t)(Nn + 1) * 4);
    float* inv   = (float*)take((size_t)Nn * 4);
    int* partial = (int*)take((size_t)NCHUNK * 1024 * 4);
    int* totals  = (int*)take(64 * 4);
    int* chunkoff= (int*)take(64 * 4);
    u16* W1t_hi  = (u16*)take(256 * 256 * 2);
    u16* W1t_lo  = (u16*)take(256 * 256 * 2);
    u16* W2t_hi  = (u16*)take(256 * 256 * 2);
    u16* W2t_lo  = (u16*)take(256 * 256 * 2);

    const int nb = (Nn + 255) / 256;
    zero_kernel<<<nb, 256, 0, stream>>>(deg, Nn);
    deg_kernel<<<E / 256, 256, 0, stream>>>(dstp, deg, E);
    invsqrt_kernel<<<nb, 256, 0, stream>>>(deg, inv, Nn);
    scan1_kernel<<<NCHUNK, 1024, 0, stream>>>(deg, partial, totals, Nn);
    scan2_kernel<<<1, 64, 0, stream>>>(totals, chunkoff, NCHUNK);
    scan3_kernel<<<nb, 256, 0, stream>>>(deg, partial, chunkoff, rptr, cursor, Nn);
    fill_kernel<<<E / 256, 256, 0, stream>>>(srcp, dstp, cursor, col, E);

    split_kernel<<<(Nn * DHID / 2 + 255) / 256, 256, 0, stream>>>(x, Ahi, Alo, Nn * DHID / 2);
    prepw_kernel<<<dim3(256, 2), 256, 0, stream>>>(W1, W2, W1t_hi, W1t_lo, W2t_hi, W2t_lo);

    const int gm = (Nn + 127) / 128;  // 391
    // layer 1
    gemm_split_kernel<<<dim3(gm, 2), 256, 0, stream>>>(Ahi, Alo, W1t_hi, W1t_lo, inv, hs, Nn);
    agg_kernel<<<(Nn + 3) / 4, 256, 0, stream>>>(hs, rptr, col, inv, b1, Ahi, Alo, nullptr, 0, Nn);
    // layer 2
    gemm_split_kernel<<<dim3(gm, 2), 256, 0, stream>>>(Ahi, Alo, W2t_hi, W2t_lo, inv, hs, Nn);
    agg_kernel<<<(Nn + 3) / 4, 256, 0, stream>>>(hs, rptr, col, inv, b2, nullptr, nullptr, out, 1, Nn);
}